// Round 1
// baseline (404.399 us; speedup 1.0000x reference)
//
#include <hip/hip_runtime.h>
#include <hip/hip_bf16.h>
#include <stdint.h>

#define D_MODEL 1024
#define NHEADS  16
#define HDIM    64
#define BATCH   4
#define SEQ     2048
#define NTOK    (BATCH*SEQ)
#define QSCALE  0.125f
#define LOG2E   1.4426950408889634f

typedef __attribute__((ext_vector_type(8))) short bf16x8;
typedef __attribute__((ext_vector_type(4))) float f32x4;
typedef __attribute__((ext_vector_type(8))) unsigned short u16x8;

static __device__ __forceinline__ unsigned short f2bf(float f) {
    union { float f; unsigned u; } v; v.f = f;
    unsigned r = v.u + 0x7FFFu + ((v.u >> 16) & 1u);
    return (unsigned short)(r >> 16);
}

#define GLDS16(g, l) __builtin_amdgcn_global_load_lds( \
    (const __attribute__((address_space(1))) void*)(g), \
    (__attribute__((address_space(3))) void*)(l), 16, 0, 0)

// ---------------- fp32 -> bf16 convert ----------------
__global__ void cvt_kernel(const float* __restrict__ in,
                           unsigned short* __restrict__ out, int n4) {
    int i = blockIdx.x * blockDim.x + threadIdx.x;
    int stride = gridDim.x * blockDim.x;
    for (; i < n4; i += stride) {
        f32x4 v = *(const f32x4*)(in + (size_t)i * 4);
        ushort4 o;
        o.x = f2bf(v.x); o.y = f2bf(v.y); o.z = f2bf(v.z); o.w = f2bf(v.w);
        *(ushort4*)(out + (size_t)i * 4) = o;
    }
}

// ---------------- NT GEMM: C[M,N] = A[M,K] * B[N,K]^T ----------------
// MODE 0: QKV epilogue -> scatter to Q/K/V [B,H,N,64] bf16, Q scaled.
// MODE 1: proj epilogue -> fp32 out + bias.
#define BM 128
#define BN 128
#define BK 64

template<int MODE>
__global__ __launch_bounds__(256, 2) void gemm_nt(
    const unsigned short* __restrict__ A,
    const unsigned short* __restrict__ B,
    int M, int N, int K,
    unsigned short* __restrict__ Qb, unsigned short* __restrict__ Kb,
    unsigned short* __restrict__ Vb,
    float* __restrict__ Out, const float* __restrict__ bias)
{
    __shared__ __attribute__((aligned(16))) unsigned short As[BM * BK];
    __shared__ __attribute__((aligned(16))) unsigned short Bs[BN * BK];

    const int bn = blockIdx.x, bm = blockIdx.y;
    const int tid = threadIdx.x;
    const int wid = tid >> 6, lane = tid & 63;
    const int wm = wid >> 1, wn = wid & 1;
    const int lr = lane & 15, lg = lane >> 4;

    const unsigned short* Ablk = A + (size_t)bm * BM * K;
    const unsigned short* Bblk = B + (size_t)bn * BN * K;

    f32x4 acc[4][4] = {};

    for (int k0 = 0; k0 < K; k0 += BK) {
        // stage A-tile and B-tile: 16 chunks of 8 rows x 64 cols each
#pragma unroll
        for (int r = 0; r < 4; ++r) {
            const int chunk = wid * 4 + r;              // wave-uniform
            const int row = chunk * 8 + (lane >> 3);
            const int col = k0 + (lane & 7) * 8;
            GLDS16(Ablk + (size_t)row * K + col, As + chunk * 512);
            GLDS16(Bblk + (size_t)row * K + col, Bs + chunk * 512);
        }
        __syncthreads();
#pragma unroll
        for (int kk = 0; kk < BK / 32; ++kk) {
            bf16x8 af[4], bfr[4];
#pragma unroll
            for (int m = 0; m < 4; ++m)
                af[m] = *(const bf16x8*)(As + (wm * 64 + m * 16 + lr) * BK + kk * 32 + lg * 8);
#pragma unroll
            for (int n = 0; n < 4; ++n)
                bfr[n] = *(const bf16x8*)(Bs + (wn * 64 + n * 16 + lr) * BK + kk * 32 + lg * 8);
#pragma unroll
            for (int m = 0; m < 4; ++m)
#pragma unroll
                for (int n = 0; n < 4; ++n)
                    acc[m][n] = __builtin_amdgcn_mfma_f32_16x16x32_bf16(
                        af[m], bfr[n], acc[m][n], 0, 0, 0);
        }
        __syncthreads();
    }

    const int row0 = bm * BM + wm * 64;
    const int col0 = bn * BN + wn * 64;
#pragma unroll
    for (int m = 0; m < 4; ++m) {
#pragma unroll
        for (int n = 0; n < 4; ++n) {
            const int row = row0 + m * 16 + lg * 4;   // + r
            const int col = col0 + n * 16 + lr;
            if (MODE == 0) {
                const int which = col >> 10;
                const int h = (col >> 6) & 15;
                const int e = col & 63;
                unsigned short* dst = (which == 0) ? Qb : (which == 1) ? Kb : Vb;
                const float sc = (which == 0) ? QSCALE : 1.0f;
                const int b = row >> 11;
                const int s = row & (SEQ - 1);
                const size_t base = ((size_t)(b * NHEADS + h) * SEQ + s) * HDIM + e;
#pragma unroll
                for (int r = 0; r < 4; ++r)
                    dst[base + (size_t)r * HDIM] = f2bf(acc[m][n][r] * sc);
            } else {
                const float bv = bias[col];
#pragma unroll
                for (int r = 0; r < 4; ++r)
                    Out[(size_t)(row + r) * N + col] = acc[m][n][r] + bv;
            }
        }
    }
}

// ---------------- flash attention forward ----------------
#define QBLK 128
#define KBLK 64
#define VPAD 72   // 144B row stride: 16B aligned, 2-way bank alias only (free)

__global__ __launch_bounds__(256, 2) void flash_fwd(
    const unsigned short* __restrict__ Q,
    const unsigned short* __restrict__ Kg,
    const unsigned short* __restrict__ Vg,
    unsigned short* __restrict__ Ob)
{
    __shared__ __attribute__((aligned(16))) unsigned short Vt[HDIM][VPAD];
    __shared__ __attribute__((aligned(16))) unsigned short Pl[4][32][VPAD];

    const int bh = blockIdx.x;
    const int q0 = blockIdx.y * QBLK;
    const int tid = threadIdx.x;
    const int wid = tid >> 6, lane = tid & 63;
    const int lr = lane & 15, lg = lane >> 4;

    const size_t bhoff = (size_t)bh * SEQ * HDIM;
    const unsigned short* Qp = Q + bhoff;
    const unsigned short* Kp = Kg + bhoff;
    const unsigned short* Vp = Vg + bhoff;

    // Q fragments held in registers for the whole kernel
    bf16x8 qf[2][2];
#pragma unroll
    for (int m = 0; m < 2; ++m)
#pragma unroll
        for (int kk = 0; kk < 2; ++kk)
            qf[m][kk] = *(const bf16x8*)(Qp + (size_t)(q0 + wid * 32 + m * 16 + lr) * HDIM + kk * 32 + lg * 8);

    f32x4 o[2][4] = {};
    float mrow[2][4], lrow[2][4];
#pragma unroll
    for (int m = 0; m < 2; ++m)
#pragma unroll
        for (int r = 0; r < 4; ++r) { mrow[m][r] = -1e30f; lrow[m][r] = 0.f; }

    for (int k0 = 0; k0 < SEQ; k0 += KBLK) {
        __syncthreads();   // protect Vt from previous iteration's readers
        // stage V-tile transposed: Vt[e][key]
#pragma unroll
        for (int it = 0; it < 2; ++it) {
            const int key = tid & 63;
            const int e0 = (tid >> 6) * 8 + it * 32;
            u16x8 v = *(const u16x8*)(Vp + (size_t)(k0 + key) * HDIM + e0);
#pragma unroll
            for (int j = 0; j < 8; ++j)
                Vt[e0 + j][key] = v[j];
        }
        __syncthreads();

        // S = Q * K^T   (K B-fragments straight from global; L2-resident)
        f32x4 s[2][4] = {};
#pragma unroll
        for (int kk = 0; kk < 2; ++kk) {
            bf16x8 kf[4];
#pragma unroll
            for (int n = 0; n < 4; ++n)
                kf[n] = *(const bf16x8*)(Kp + (size_t)(k0 + n * 16 + lr) * HDIM + kk * 32 + lg * 8);
#pragma unroll
            for (int m = 0; m < 2; ++m)
#pragma unroll
                for (int n = 0; n < 4; ++n)
                    s[m][n] = __builtin_amdgcn_mfma_f32_16x16x32_bf16(
                        qf[m][kk], kf[n], s[m][n], 0, 0, 0);
        }

        // online softmax (rows live in 16-lane col-groups sharing lg)
#pragma unroll
        for (int m = 0; m < 2; ++m) {
            float tm[4], rs[4];
#pragma unroll
            for (int r = 0; r < 4; ++r)
                tm[r] = fmaxf(fmaxf(s[m][0][r], s[m][1][r]),
                              fmaxf(s[m][2][r], s[m][3][r]));
#pragma unroll
            for (int r = 0; r < 4; ++r) {
#pragma unroll
                for (int msk = 1; msk < 16; msk <<= 1)
                    tm[r] = fmaxf(tm[r], __shfl_xor(tm[r], msk));
            }
#pragma unroll
            for (int r = 0; r < 4; ++r) {
                const float mnew = fmaxf(mrow[m][r], tm[r]);
                const float sc = exp2f((mrow[m][r] - mnew) * LOG2E);
                mrow[m][r] = mnew;
                lrow[m][r] *= sc;
#pragma unroll
                for (int n = 0; n < 4; ++n)
                    o[m][n][r] *= sc;
                rs[r] = 0.f;
            }
#pragma unroll
            for (int n = 0; n < 4; ++n)
#pragma unroll
                for (int r = 0; r < 4; ++r) {
                    const float p = exp2f((s[m][n][r] - mrow[m][r]) * LOG2E);
                    rs[r] += p;
                    Pl[wid][m * 16 + lg * 4 + r][n * 16 + lr] = f2bf(p);
                }
#pragma unroll
            for (int r = 0; r < 4; ++r) {
#pragma unroll
                for (int msk = 1; msk < 16; msk <<= 1)
                    rs[r] += __shfl_xor(rs[r], msk);
                lrow[m][r] += rs[r];
            }
        }

        // O += P * V   (P via per-wave LDS tile, V via transposed LDS tile)
#pragma unroll
        for (int kk = 0; kk < 2; ++kk) {
            bf16x8 pa[2], vb[4];
#pragma unroll
            for (int m = 0; m < 2; ++m)
                pa[m] = *(const bf16x8*)(&Pl[wid][m * 16 + lr][kk * 32 + lg * 8]);
#pragma unroll
            for (int n = 0; n < 4; ++n)
                vb[n] = *(const bf16x8*)(&Vt[n * 16 + lr][kk * 32 + lg * 8]);
#pragma unroll
            for (int m = 0; m < 2; ++m)
#pragma unroll
                for (int n = 0; n < 4; ++n)
                    o[m][n] = __builtin_amdgcn_mfma_f32_16x16x32_bf16(
                        pa[m], vb[n], o[m][n], 0, 0, 0);
        }
    }

    // epilogue: normalize, write [B,N,H*hd] bf16
    const int b = bh >> 4, h = bh & 15;
    float rin[2][4];
#pragma unroll
    for (int m = 0; m < 2; ++m)
#pragma unroll
        for (int r = 0; r < 4; ++r)
            rin[m][r] = 1.0f / lrow[m][r];
#pragma unroll
    for (int m = 0; m < 2; ++m)
#pragma unroll
        for (int n = 0; n < 4; ++n)
#pragma unroll
            for (int r = 0; r < 4; ++r) {
                const int srow = q0 + wid * 32 + m * 16 + lg * 4 + r;
                const size_t idx = ((size_t)(b * SEQ + srow)) * D_MODEL + h * HDIM + n * 16 + lr;
                Ob[idx] = f2bf(o[m][n][r] * rin[m][r]);
            }
}

// ---------------- launch ----------------
extern "C" void kernel_launch(void* const* d_in, const int* in_sizes, int n_in,
                              void* d_out, int out_size, void* d_ws, size_t ws_size,
                              hipStream_t stream)
{
    const float* x      = (const float*)d_in[0];
    const float* w_qkv  = (const float*)d_in[1];
    const float* w_proj = (const float*)d_in[2];
    const float* b_proj = (const float*)d_in[3];
    float* out = (float*)d_out;

    char* ws = (char*)d_ws;
    size_t off = 0;
    auto alloc = [&](size_t elems) -> unsigned short* {
        unsigned short* p = (unsigned short*)(ws + off);
        off += ((elems * 2 + 255) & ~(size_t)255);
        return p;
    };
    unsigned short* xb  = alloc((size_t)NTOK * D_MODEL);
    unsigned short* wqb = alloc((size_t)3 * D_MODEL * D_MODEL);
    unsigned short* wpb = alloc((size_t)D_MODEL * D_MODEL);
    unsigned short* Qb  = alloc((size_t)NTOK * D_MODEL);
    unsigned short* Kb  = alloc((size_t)NTOK * D_MODEL);
    unsigned short* Vb  = alloc((size_t)NTOK * D_MODEL);
    unsigned short* Ab  = alloc((size_t)NTOK * D_MODEL);

    cvt_kernel<<<2048, 256, 0, stream>>>(x, xb, NTOK * D_MODEL / 4);
    cvt_kernel<<<1024, 256, 0, stream>>>(w_qkv, wqb, 3 * D_MODEL * D_MODEL / 4);
    cvt_kernel<<<256, 256, 0, stream>>>(w_proj, wpb, D_MODEL * D_MODEL / 4);

    gemm_nt<0><<<dim3(3 * D_MODEL / BN, NTOK / BM), 256, 0, stream>>>(
        xb, wqb, NTOK, 3 * D_MODEL, D_MODEL, Qb, Kb, Vb, nullptr, nullptr);

    flash_fwd<<<dim3(BATCH * NHEADS, SEQ / QBLK), 256, 0, stream>>>(Qb, Kb, Vb, Ab);

    gemm_nt<1><<<dim3(D_MODEL / BN, NTOK / BM), 256, 0, stream>>>(
        Ab, wpb, NTOK, D_MODEL, D_MODEL, nullptr, nullptr, nullptr, out, b_proj);
}

// Round 3
// 296.646 us; speedup vs baseline: 1.3632x; 1.3632x over previous
//
#include <hip/hip_runtime.h>
#include <hip/hip_bf16.h>
#include <stdint.h>

#define D_MODEL 1024
#define NHEADS  16
#define HDIM    64
#define BATCH   4
#define SEQ     2048
#define NTOK    (BATCH*SEQ)
#define QSCALE  0.125f
#define LOG2E   1.4426950408889634f

typedef __attribute__((ext_vector_type(8)))  short bf16x8;
typedef __attribute__((ext_vector_type(4)))  short bf16x4;
typedef __attribute__((ext_vector_type(4)))  float f32x4;
typedef __attribute__((ext_vector_type(16))) float f32x16;

static __device__ __forceinline__ unsigned short f2bf(float f) {
    union { float f; unsigned u; } v; v.f = f;
    unsigned r = v.u + 0x7FFFu + ((v.u >> 16) & 1u);
    return (unsigned short)(r >> 16);
}

static __device__ __forceinline__ unsigned cvtpk_bf16(float lo, float hi) {
    unsigned r;
    asm("v_cvt_pk_bf16_f32 %0, %1, %2" : "=v"(r) : "v"(lo), "v"(hi));
    return r;
}

#define GLDS16(g, l) __builtin_amdgcn_global_load_lds( \
    (const __attribute__((address_space(1))) void*)(g), \
    (__attribute__((address_space(3))) void*)(l), 16, 0, 0)

// ---------------- fp32 -> bf16 convert ----------------
__global__ void cvt_kernel(const float* __restrict__ in,
                           unsigned short* __restrict__ out, int n4) {
    int i = blockIdx.x * blockDim.x + threadIdx.x;
    int stride = gridDim.x * blockDim.x;
    for (; i < n4; i += stride) {
        f32x4 v = *(const f32x4*)(in + (size_t)i * 4);
        ushort4 o;
        o.x = f2bf(v.x); o.y = f2bf(v.y); o.z = f2bf(v.z); o.w = f2bf(v.w);
        *(ushort4*)(out + (size_t)i * 4) = o;
    }
}

// ---------------- NT GEMM: C[M,N] = A[M,K] * B[N,K]^T ----------------
// MODE 0: QKV epilogue -> Q,K as [bh][seq][64] bf16 (Q scaled by 1/8*log2e),
//         V transposed to [bh][64][seq] bf16.
// MODE 1: proj epilogue -> fp32 out + bias.
#define BM 128
#define BN 128
#define BK 64

template<int MODE>
__global__ __launch_bounds__(256, 2) void gemm_nt(
    const unsigned short* __restrict__ A,
    const unsigned short* __restrict__ B,
    int M, int N, int K,
    unsigned short* __restrict__ Qb, unsigned short* __restrict__ Kb,
    unsigned short* __restrict__ Vb,
    float* __restrict__ Out, const float* __restrict__ bias)
{
    __shared__ __attribute__((aligned(16))) unsigned short As[BM * BK];
    __shared__ __attribute__((aligned(16))) unsigned short Bs[BN * BK];

    const int bn = blockIdx.x, bm = blockIdx.y;
    const int tid = threadIdx.x;
    const int wid = tid >> 6, lane = tid & 63;
    const int wm = wid >> 1, wn = wid & 1;
    const int lr = lane & 15, lg = lane >> 4;

    const unsigned short* Ablk = A + (size_t)bm * BM * K;
    const unsigned short* Bblk = B + (size_t)bn * BN * K;

    f32x4 acc[4][4] = {};

    for (int k0 = 0; k0 < K; k0 += BK) {
#pragma unroll
        for (int r = 0; r < 4; ++r) {
            const int chunk = wid * 4 + r;              // wave-uniform
            const int row = chunk * 8 + (lane >> 3);
            const int colk = k0 + (lane & 7) * 8;
            GLDS16(Ablk + (size_t)row * K + colk, As + chunk * 512);
            GLDS16(Bblk + (size_t)row * K + colk, Bs + chunk * 512);
        }
        __syncthreads();
#pragma unroll
        for (int kk = 0; kk < BK / 32; ++kk) {
            bf16x8 af[4], bfr[4];
#pragma unroll
            for (int m = 0; m < 4; ++m)
                af[m] = *(const bf16x8*)(As + (wm * 64 + m * 16 + lr) * BK + kk * 32 + lg * 8);
#pragma unroll
            for (int n = 0; n < 4; ++n)
                bfr[n] = *(const bf16x8*)(Bs + (wn * 64 + n * 16 + lr) * BK + kk * 32 + lg * 8);
#pragma unroll
            for (int m = 0; m < 4; ++m)
#pragma unroll
                for (int n = 0; n < 4; ++n)
                    acc[m][n] = __builtin_amdgcn_mfma_f32_16x16x32_bf16(
                        af[m], bfr[n], acc[m][n], 0, 0, 0);
        }
        __syncthreads();
    }

    const int row0 = bm * BM + wm * 64;
    const int col0 = bn * BN + wn * 64;
#pragma unroll
    for (int m = 0; m < 4; ++m) {
#pragma unroll
        for (int n = 0; n < 4; ++n) {
            const int row = row0 + m * 16 + lg * 4;   // + r
            const int col = col0 + n * 16 + lr;
            if (MODE == 0) {
                const int which = col >> 10;
                const int h = (col >> 6) & 15;
                const int e = col & 63;
                const int b = row >> 11;
                const int s = row & (SEQ - 1);
                if (which == 2) {
                    // V transposed: [bh][e][seq], 4 consecutive seq -> ushort4
                    ushort4 w;
                    w.x = f2bf(acc[m][n][0]); w.y = f2bf(acc[m][n][1]);
                    w.z = f2bf(acc[m][n][2]); w.w = f2bf(acc[m][n][3]);
                    *(ushort4*)(Vb + ((size_t)((b * NHEADS + h) * HDIM + e)) * SEQ + s) = w;
                } else {
                    unsigned short* dst = (which == 0) ? Qb : Kb;
                    const float sc = (which == 0) ? (QSCALE * LOG2E) : 1.0f;
                    const size_t base = ((size_t)(b * NHEADS + h) * SEQ + s) * HDIM + e;
#pragma unroll
                    for (int r = 0; r < 4; ++r)
                        dst[base + (size_t)r * HDIM] = f2bf(acc[m][n][r] * sc);
                }
            } else {
                const float bv = bias[col];
#pragma unroll
                for (int r = 0; r < 4; ++r)
                    Out[(size_t)(row + r) * N + col] = acc[m][n][r] + bv;
            }
        }
    }
}

// ---------------- flash attention v3: zero-LDS, swapped QK^T ----------------
// 1 wave/block, 64 q-rows/wave (2 m-tiles of 32). Lane owns q-row (lane&31).
// All cross-lane via __shfl_xor(.,32) (guaranteed semantics). P-fragments are
// packed lane-locally into their NATIVE key slots crow(j,hi); the V^T
// A-fragment loads the matching key order, so the PV contraction is correct
// independent of the MFMA k-slot permutation (sigma-invariance).
__global__ __launch_bounds__(64, 2) void flash_fwd3(
    const unsigned short* __restrict__ Q,    // [bh][seq][64], pre-scaled by 1/8*log2e
    const unsigned short* __restrict__ Kg,   // [bh][seq][64]
    const unsigned short* __restrict__ Vt,   // [bh][64][seq]
    unsigned short* __restrict__ Ob)         // [B, seq, 1024]
{
    const int bh = blockIdx.x;
    const int qt = blockIdx.y;
    const int lane = threadIdx.x;
    const int col = lane & 31;
    const int hi  = lane >> 5;

    const size_t bhoff = (size_t)bh * SEQ * HDIM;
    const unsigned short* Qp = Q + bhoff;
    const unsigned short* Kp = Kg + bhoff;
    const unsigned short* Vp = Vt + bhoff;

    const int q0 = qt * 64;

    bf16x8 qf[2][4];
#pragma unroll
    for (int mt = 0; mt < 2; ++mt)
#pragma unroll
        for (int c = 0; c < 4; ++c)
            qf[mt][c] = *(const bf16x8*)(Qp + (size_t)(q0 + mt * 32 + col) * HDIM + c * 16 + hi * 8);

    f32x16 o[2][2] = {};
    float mr[2] = { -1e30f, -1e30f };
    float ls[2] = { 0.f, 0.f };

    for (int k0 = 0; k0 < SEQ; k0 += 32) {
        // S^T = K * Q^T : rows=keys (C/D reg pattern), cols=q-rows (lane&31)
        bf16x8 kf[4];
#pragma unroll
        for (int c = 0; c < 4; ++c)
            kf[c] = *(const bf16x8*)(Kp + (size_t)(k0 + col) * HDIM + c * 16 + hi * 8);
        f32x16 s[2] = {};
#pragma unroll
        for (int c = 0; c < 4; ++c) {
            s[0] = __builtin_amdgcn_mfma_f32_32x32x16_bf16(kf[c], qf[0][c], s[0], 0, 0, 0);
            s[1] = __builtin_amdgcn_mfma_f32_32x32x16_bf16(kf[c], qf[1][c], s[1], 0, 0, 0);
        }

        // V^T A-fragments in crow() key order: slot (hi,j<4) <- key ks*16+4*hi+j,
        // slot (hi,j>=4) <- key ks*16+8+4*hi+(j-4). Matches P-pack below.
        bf16x8 vA[2][2];
#pragma unroll
        for (int ks = 0; ks < 2; ++ks)
#pragma unroll
            for (int nt = 0; nt < 2; ++nt) {
                const unsigned short* vb =
                    Vp + (size_t)(nt * 32 + col) * SEQ + k0 + ks * 16 + hi * 4;
                union { bf16x4 h[2]; bf16x8 v; } t;
                t.h[0] = *(const bf16x4*)(vb);
                t.h[1] = *(const bf16x4*)(vb + 8);
                vA[ks][nt] = t.v;
            }

#pragma unroll
        for (int mt = 0; mt < 2; ++mt) {
            // row max over this lane's 16 keys, then cross-half exchange
            float a0 = fmaxf(s[mt][0], s[mt][1]),  a1 = fmaxf(s[mt][2], s[mt][3]);
            float a2 = fmaxf(s[mt][4], s[mt][5]),  a3 = fmaxf(s[mt][6], s[mt][7]);
            float a4 = fmaxf(s[mt][8], s[mt][9]),  a5 = fmaxf(s[mt][10], s[mt][11]);
            float a6 = fmaxf(s[mt][12], s[mt][13]), a7 = fmaxf(s[mt][14], s[mt][15]);
            float tm = fmaxf(fmaxf(fmaxf(a0, a1), fmaxf(a2, a3)),
                             fmaxf(fmaxf(a4, a5), fmaxf(a6, a7)));
            tm = fmaxf(tm, __shfl_xor(tm, 32));

            // defer-max (T13): only rescale when max grew past threshold
            if (!__all(tm <= mr[mt] + 8.0f)) {
                const float mnew = fmaxf(mr[mt], tm);
                const float sc = exp2f(mr[mt] - mnew);
#pragma unroll
                for (int nt = 0; nt < 2; ++nt)
#pragma unroll
                    for (int i = 0; i < 16; ++i) o[mt][nt][i] *= sc;
                ls[mt] *= sc;
                mr[mt] = mnew;
            }

            float p[16]; float rs = 0.f;
#pragma unroll
            for (int i = 0; i < 16; ++i) {
                p[i] = exp2f(s[mt][i] - mr[mt]);
                rs += p[i];
            }
            const float rso = __shfl_xor(rs, 32);
            ls[mt] += rs + rso;

            // pack P lane-locally into native key slots (no cross-lane):
            // f0 slot j <- p[j] (keys crow(j,hi)), f1 slot j <- p[8+j] (+16)
            union { unsigned w[4]; bf16x8 v; } f0, f1;
#pragma unroll
            for (int d = 0; d < 4; ++d) {
                f0.w[d] = cvtpk_bf16(p[2 * d],     p[2 * d + 1]);
                f1.w[d] = cvtpk_bf16(p[8 + 2 * d], p[9 + 2 * d]);
            }

            // O^T += V^T * P^T : rows=d-dims, cols=q-rows
#pragma unroll
            for (int nt = 0; nt < 2; ++nt) {
                o[mt][nt] = __builtin_amdgcn_mfma_f32_32x32x16_bf16(vA[0][nt], f0.v, o[mt][nt], 0, 0, 0);
                o[mt][nt] = __builtin_amdgcn_mfma_f32_32x32x16_bf16(vA[1][nt], f1.v, o[mt][nt], 0, 0, 0);
            }
        }
    }

    // epilogue: per-lane 1/l, write [B,N,C] bf16
    const int b = bh >> 4, h = bh & 15;
#pragma unroll
    for (int mt = 0; mt < 2; ++mt) {
        const float inv = 1.0f / ls[mt];
        const size_t tok = (size_t)b * SEQ + q0 + mt * 32 + col;
#pragma unroll
        for (int nt = 0; nt < 2; ++nt)
#pragma unroll
            for (int rq = 0; rq < 4; ++rq) {
                ushort4 w;
                w.x = f2bf(o[mt][nt][rq * 4 + 0] * inv);
                w.y = f2bf(o[mt][nt][rq * 4 + 1] * inv);
                w.z = f2bf(o[mt][nt][rq * 4 + 2] * inv);
                w.w = f2bf(o[mt][nt][rq * 4 + 3] * inv);
                // D row = (reg&3) + 8*(reg>>2) + 4*hi  ->  d = nt*32 + rq*8 + hi*4 + j
                *(ushort4*)(Ob + tok * D_MODEL + h * HDIM + nt * 32 + rq * 8 + hi * 4) = w;
            }
    }
}

// ---------------- launch ----------------
extern "C" void kernel_launch(void* const* d_in, const int* in_sizes, int n_in,
                              void* d_out, int out_size, void* d_ws, size_t ws_size,
                              hipStream_t stream)
{
    const float* x      = (const float*)d_in[0];
    const float* w_qkv  = (const float*)d_in[1];
    const float* w_proj = (const float*)d_in[2];
    const float* b_proj = (const float*)d_in[3];
    float* out = (float*)d_out;

    char* ws = (char*)d_ws;
    size_t off = 0;
    auto alloc = [&](size_t elems) -> unsigned short* {
        unsigned short* p = (unsigned short*)(ws + off);
        off += ((elems * 2 + 255) & ~(size_t)255);
        return p;
    };
    unsigned short* xb  = alloc((size_t)NTOK * D_MODEL);
    unsigned short* wqb = alloc((size_t)3 * D_MODEL * D_MODEL);
    unsigned short* wpb = alloc((size_t)D_MODEL * D_MODEL);
    unsigned short* Qb  = alloc((size_t)NTOK * D_MODEL);
    unsigned short* Kb  = alloc((size_t)NTOK * D_MODEL);
    unsigned short* Vb  = alloc((size_t)NTOK * D_MODEL);   // transposed [bh][64][seq]
    unsigned short* Ab  = alloc((size_t)NTOK * D_MODEL);

    cvt_kernel<<<2048, 256, 0, stream>>>(x, xb, NTOK * D_MODEL / 4);
    cvt_kernel<<<1024, 256, 0, stream>>>(w_qkv, wqb, 3 * D_MODEL * D_MODEL / 4);
    cvt_kernel<<<256, 256, 0, stream>>>(w_proj, wpb, D_MODEL * D_MODEL / 4);

    gemm_nt<0><<<dim3(3 * D_MODEL / BN, NTOK / BM), 256, 0, stream>>>(
        xb, wqb, NTOK, 3 * D_MODEL, D_MODEL, Qb, Kb, Vb, nullptr, nullptr);

    flash_fwd3<<<dim3(BATCH * NHEADS, SEQ / 64), 64, 0, stream>>>(Qb, Kb, Vb, Ab);

    gemm_nt<1><<<dim3(D_MODEL / BN, NTOK / BM), 256, 0, stream>>>(
        Ab, wpb, NTOK, D_MODEL, D_MODEL, nullptr, nullptr, nullptr, out, b_proj);
}